// Round 6
// baseline (146.344 us; speedup 1.0000x reference)
//
#include <hip/hip_runtime.h>
#include <hip/hip_fp16.h>

// NCC loss: 9^3 box sums of {I, J, I*I, J*J, I*J}, per-voxel cc, -mean(cc).
// Dims: C=2, D=192, H=224, W=192, fp32. Separable box filter:
//   K1 (k_hwsum): ZERO-LDS. wave = one d-slice row strip, 64 lanes x 3 px = W.
//                 H-sum: running sum, add row h+4 / subtract re-loaded row h-4
//                 (both prefetched 1 step ahead; drop-row re-read is L3-hot).
//                 W-sum: 6 ds_bpermute shuffles per field (o1 = Tm+T+Tp;
//                 o0 = o1 + z(l-2) - z(l+1); o2 = o1 - x(l-1) + x(l+2)).
//                 -> fp16 2D sums. No LDS, no barriers, no VGPR ring.
//   K2 (k_dsum):  D-sum — barrier-free streaming register ring + cc + reduce.

#define C2   2
#define DDIM 192
#define HDIM 224
#define WDIM 192
#define HWN  (HDIM*WDIM)              // 43008
#define VOL  ((size_t)DDIM*HWN)       // 8257536
#define RAD  4
#define WINV (1.0f/729.0f)

#define HT1  14     // K1 h-strip per wave (224/14 = 16 strips -> 6 waves/SIMD)

// ---------------- K1: H-sum + W-sum of 5 product fields, 1 wave/row ----------------
// grid: ((nd+3)/4, HDIM/HT1, C2); block: 256 = 4 waves = 4 consecutive d-slices
// buf layout (fp16): [f][c][bd][h][w], bd = d - d0 + 4, fstride = C2*bufD*HWN
__global__ __launch_bounds__(256, 5)
void k_hwsum(const float* __restrict__ I, const float* __restrict__ J,
             __half* __restrict__ buf, int d0, int dbeg, int dend, int bufD)
{
    const int tid = threadIdx.x;
    const int wv  = tid >> 6;         // wave within block
    const int l   = tid & 63;         // lane
    const int w0  = 3 * l;            // first of 3 owned pixels
    int d = dbeg + 4*blockIdx.x + wv;
    if (d >= dend) d = dend - 1;      // duplicate wave: writes identical data
    const int h0 = blockIdx.y * HT1;
    const int c  = blockIdx.z;

    const float* Ib = I + (size_t)c*VOL + (size_t)d*HWN + w0;
    const float* Jb = J + (size_t)c*VOL + (size_t)d*HWN + w0;

    // running H-sums for the 3 owned pixels, 5 fields
    float3 rs0{0,0,0}, rs1{0,0,0}, rs2{0,0,0}, rs3{0,0,0}, rs4{0,0,0};

    // warm-up: accumulate rows h0-4 .. h0+3 (zero padded)
    #pragma unroll
    for (int k = 0; k < 8; ++k) {
        const int h = h0 - RAD + k;
        float3 iv{0,0,0}, jv{0,0,0};
        if (h >= 0 && h < HDIM) {
            iv = *(const float3*)(Ib + (size_t)h*WDIM);
            jv = *(const float3*)(Jb + (size_t)h*WDIM);
        }
        rs0.x += iv.x;      rs0.y += iv.y;      rs0.z += iv.z;
        rs1.x += jv.x;      rs1.y += jv.y;      rs1.z += jv.z;
        rs2.x += iv.x*iv.x; rs2.y += iv.y*iv.y; rs2.z += iv.z*iv.z;
        rs3.x += jv.x*jv.x; rs3.y += jv.y*jv.y; rs3.z += jv.z*jv.z;
        rs4.x += iv.x*jv.x; rs4.y += iv.y*jv.y; rs4.z += iv.z*jv.z;
    }

    // prefetch step-0's add row (h0+4, always valid) and drop row (h0-4)
    float3 nai{0,0,0}, naj{0,0,0}, ndi{0,0,0}, ndj{0,0,0};
    {
        const int ha = h0 + RAD;
        nai = *(const float3*)(Ib + (size_t)ha*WDIM);
        naj = *(const float3*)(Jb + (size_t)ha*WDIM);
        const int hd = h0 - RAD;
        if (hd >= 0) {
            ndi = *(const float3*)(Ib + (size_t)hd*WDIM);
            ndj = *(const float3*)(Jb + (size_t)hd*WDIM);
        }
    }

    const size_t fstride = (size_t)C2*bufD*HWN;
    __half* ob = buf + ((size_t)c*bufD + (size_t)(d - d0 + RAD))*HWN + w0;

    const bool m1m = (l >= 1), m2m = (l >= 2);
    const bool m1p = (l <= 62), m2p = (l <= 61);

    for (int i = 0; i < HT1; ++i) {
        const int h = h0 + i;
        const float3 ai = nai, aj = naj, di = ndi, dj = ndj;

        // prefetch next step's rows (hides L2/L3 latency under this step)
        nai = {0,0,0}; naj = {0,0,0}; ndi = {0,0,0}; ndj = {0,0,0};
        if (i + 1 < HT1) {
            const int ha = h + 1 + RAD;
            if (ha < HDIM) {
                nai = *(const float3*)(Ib + (size_t)ha*WDIM);
                naj = *(const float3*)(Jb + (size_t)ha*WDIM);
            }
            const int hd = h + 1 - RAD;
            if (hd >= 0) {
                ndi = *(const float3*)(Ib + (size_t)hd*WDIM);
                ndj = *(const float3*)(Jb + (size_t)hd*WDIM);
            }
        }

        // add row h+4 products
        rs0.x += ai.x;      rs0.y += ai.y;      rs0.z += ai.z;
        rs1.x += aj.x;      rs1.y += aj.y;      rs1.z += aj.z;
        rs2.x += ai.x*ai.x; rs2.y += ai.y*ai.y; rs2.z += ai.z*ai.z;
        rs3.x += aj.x*aj.x; rs3.y += aj.y*aj.y; rs3.z += aj.z*aj.z;
        rs4.x += ai.x*aj.x; rs4.y += ai.y*aj.y; rs4.z += ai.z*aj.z;

        // W-sum via shuffles + store, per field
        #define WSUM_STORE(RS, F)                                            \
        {                                                                    \
            const float T = RS.x + RS.y + RS.z;                              \
            float Tm  = __shfl(T,    l-1); Tm  = m1m ? Tm  : 0.f;            \
            float Tp  = __shfl(T,    l+1); Tp  = m1p ? Tp  : 0.f;            \
            float z2m = __shfl(RS.z, l-2); z2m = m2m ? z2m : 0.f;            \
            float z1p = __shfl(RS.z, l+1); z1p = m1p ? z1p : 0.f;            \
            float x1m = __shfl(RS.x, l-1); x1m = m1m ? x1m : 0.f;            \
            float x2p = __shfl(RS.x, l+2); x2p = m2p ? x2p : 0.f;            \
            const float o1 = Tm + T + Tp;                                    \
            const float o0 = o1 + z2m - z1p;                                 \
            const float o2 = o1 - x1m + x2p;                                 \
            __half* pf = ob + (size_t)F*fstride + (size_t)h*WDIM;            \
            *reinterpret_cast<__half2*>(pf) = __floats2half2_rn(o0, o1);     \
            pf[2] = __float2half_rn(o2);                                     \
        }
        WSUM_STORE(rs0, 0)
        WSUM_STORE(rs1, 1)
        WSUM_STORE(rs2, 2)
        WSUM_STORE(rs3, 3)
        WSUM_STORE(rs4, 4)
        #undef WSUM_STORE

        // drop row h-4 products (di/dj re-loaded from cache, not ringed)
        rs0.x -= di.x;      rs0.y -= di.y;      rs0.z -= di.z;
        rs1.x -= dj.x;      rs1.y -= dj.y;      rs1.z -= dj.z;
        rs2.x -= di.x*di.x; rs2.y -= di.y*di.y; rs2.z -= di.z*di.z;
        rs3.x -= dj.x*dj.x; rs3.y -= dj.y*dj.y; rs3.z -= dj.z*dj.z;
        rs4.x -= di.x*dj.x; rs4.y -= di.y*dj.y; rs4.z -= di.z*dj.z;
    }
}

// -------- K2: D-sum (register ring) + cc + block reduce — no LDS, no syncs --------
// grid: (HWN/256, nsub, C2); block: 256 threads
__global__ __launch_bounds__(256)
void k_dsum(const __half* __restrict__ buf, double* __restrict__ gacc,
            int d0, int bufD, int DS)
{
    const int tid = threadIdx.x;
    const int pix = blockIdx.x*256 + tid;     // (h,w) flat, HWN = 168*256 exact
    const int c   = blockIdx.z;
    const int ds0 = d0 + blockIdx.y*DS;

    const size_t fstride = (size_t)C2*bufD*HWN;
    const __half* base = buf + (size_t)c*bufD*HWN + pix;

    float ring[5][9];
    float rs[5] = {0.f,0.f,0.f,0.f,0.f};
    float acc = 0.f;

    // warm-up: slices ds0-4 .. ds0+3
    #pragma unroll
    for (int k = 0; k < 8; ++k) {
        const int dd = ds0 - RAD + k;
        float v[5] = {0.f,0.f,0.f,0.f,0.f};
        if ((unsigned)dd < (unsigned)DDIM) {
            const __half* pp = base + (size_t)(dd - d0 + RAD)*HWN;
            #pragma unroll
            for (int f = 0; f < 5; ++f) v[f] = __half2float(pp[(size_t)f*fstride]);
        }
        #pragma unroll
        for (int f = 0; f < 5; ++f) { ring[f][k] = v[f]; rs[f] += v[f]; }
    }

    int i = 0;
    while (i < DS) {
        #pragma unroll
        for (int p = 0; p < 9; ++p) {   // i == p (mod 9) whenever body runs
            if (i < DS) {
                const int dd = ds0 + i + RAD;
                float v[5] = {0.f,0.f,0.f,0.f,0.f};
                if (dd < DDIM) {
                    const __half* pp = base + (size_t)(dd - d0 + RAD)*HWN;
                    #pragma unroll
                    for (int f = 0; f < 5; ++f) v[f] = __half2float(pp[(size_t)f*fstride]);
                }
                float S[5];
                #pragma unroll
                for (int f = 0; f < 5; ++f) {
                    rs[f] += v[f];              // full 9x9x9 sum at dd-4
                    S[f] = rs[f];
                    rs[f] -= ring[f][p];        // drop slice dd-8
                    ring[f][(p+8)%9] = v[f];    // keep slice dd
                }
                const float uI    = S[0]*WINV;
                const float uJ    = S[1]*WINV;
                const float cross = S[4] - uJ*S[0];
                const float Iv    = S[2] - uI*S[0];
                const float Jv    = S[3] - uJ*S[1];
                acc += cross*cross / (Iv*Jv + 1e-5f);
                ++i;
            }
        }
    }

    // block reduction -> one double atomic per block
    __shared__ float wred[4];
    #pragma unroll
    for (int off = 32; off > 0; off >>= 1) acc += __shfl_down(acc, off);
    if ((tid & 63) == 0) wred[tid >> 6] = acc;
    __syncthreads();
    if (tid == 0) {
        const float sum = wred[0] + wred[1] + wred[2] + wred[3];
        atomicAdd(gacc, (double)sum);
    }
}

__global__ void k_fin(const double* __restrict__ gacc, float* __restrict__ out)
{
    out[0] = (float)(-gacc[0] / (double)((size_t)C2*DDIM*HDIM*WDIM));
}

extern "C" void kernel_launch(void* const* d_in, const int* in_sizes, int n_in,
                              void* d_out, int out_size, void* d_ws, size_t ws_size,
                              hipStream_t stream)
{
    if (n_in < 2) return;
    const float* I = (const float*)d_in[0];
    const float* J = (const float*)d_in[1];
    float* out = (float*)d_out;
    double* gacc = (double*)d_ws;
    __half* buf = (__half*)((char*)d_ws + 256);

    // choose D-chunk so the 5-field fp16 2D-summed buffer fits ws
    static const int cands[] = {192, 96, 48, 24, 12, 6, 4, 2, 1};
    int Dc = 0;
    for (int c : cands) {
        const size_t need = 256 + (size_t)5*C2*(c+8)*HWN*sizeof(__half);
        if (need <= ws_size) { Dc = c; break; }
    }
    if (Dc == 0) return;  // ws too small — cannot run

    hipMemsetAsync(d_ws, 0, 256, stream);   // zero the double accumulator

    const int DS   = (Dc % 48 == 0) ? 48 : Dc;  // K2 sub-chunk along D
    const int nsub = Dc / DS;
    const int bufD = Dc + 8;

    for (int d0 = 0; d0 < DDIM; d0 += Dc) {
        const int dbeg = (d0 - RAD < 0) ? 0 : d0 - RAD;
        const int dend = (d0 + Dc + RAD > DDIM) ? DDIM : d0 + Dc + RAD;
        const int nd   = dend - dbeg;
        dim3 g1((nd + 3)/4, HDIM/HT1, C2);
        k_hwsum<<<g1, dim3(256,1,1), 0, stream>>>(I, J, buf, d0, dbeg, dend, bufD);
        dim3 g2(HWN/256, nsub, C2);
        k_dsum<<<g2, dim3(256,1,1), 0, stream>>>(buf, gacc, d0, bufD, DS);
    }
    k_fin<<<1,1,0,stream>>>(gacc, out);
}

// Round 7
// 128.830 us; speedup vs baseline: 1.1359x; 1.1359x over previous
//
#include <hip/hip_runtime.h>
#include <hip/hip_fp16.h>

// NCC loss: 9^3 box sums of {I, J, I*I, J*J, I*J}, per-voxel cc, -mean(cc).
// Dims: C=2, D=192, H=224, W=192, fp32. Separable box filter, 2 passes:
//   K1 (k_hwsum): 2px/thread. H-sum (float2 register ring, 1-step prefetch) +
//                 W-sum (LDS b64 taps, parity double-buffer, one barrier/step).
//   K2 (k_dsum):  D-sum — barrier-free streaming register ring + cc + reduce.
// Intermediate layout: VOXEL-INTERLEAVED fp16 [c][d][h][w][f] (10 B/voxel) —
// collapses 15 concurrent HBM streams (5 field planes x W + reads) to 3,
// targeting the ~2.9 TB/s many-stream write cap seen in rounds 2-6.

#define C2   2
#define DDIM 192
#define HDIM 224
#define WDIM 192
#define HWN  (HDIM*WDIM)              // 43008
#define VOL  ((size_t)DDIM*HWN)       // 8257536
#define RAD  4
#define WINV (1.0f/729.0f)

#define HT1  28     // K1 h-chunk per block (224/28 = 8)
#define NROW 200    // padded LDS row stride in floats: 4 | 192 | 4

// ---------------- K1: H-sum + W-sum of 5 product fields, 2px/thread ----------------
// grid: ((nd+1)/2, HDIM/HT1, C2); block: 192 = 2 slices x 96 pairs
// buf layout (fp16): [c][bd][h][w][f], bd = d - d0 + 4 (record = 5 halfs)
__global__ __launch_bounds__(192)
void k_hwsum(const float* __restrict__ I, const float* __restrict__ J,
             __half* __restrict__ buf, int d0, int dbeg, int dend, int bufD)
{
    const int tx = threadIdx.x;
    const int s  = tx / 96;           // d-slice within pair
    const int p  = tx % 96;           // w-pair index
    const int w0 = 2 * p;
    int d = dbeg + 2*blockIdx.x + s;
    if (d >= dend) d = dend - 1;      // duplicate of sibling thread: benign
    const int h0 = blockIdx.y * HT1;
    const int c  = blockIdx.z;

    __shared__ float row[2][2][5][NROW];   // [slice][parity][field], 16 KB

    // zero the W-halo pads (idx 0..3 and 196..199 of every row)
    for (int t = tx; t < 2*2*5*8; t += 192) {
        const int k    = t & 7;
        const int rest = t >> 3;                      // (s*2+b)*5+f
        const int pos  = (k < 4) ? k : (192 + k);     // 0..3, 196..199
        (&row[0][0][0][0])[rest*NROW + pos] = 0.f;
    }
    __syncthreads();

    const float* Ib = I + (size_t)c*VOL + (size_t)d*HWN + w0;
    const float* Jb = J + (size_t)c*VOL + (size_t)d*HWN + w0;

    float2 ring[5][9];
    float2 rs[5];
    #pragma unroll
    for (int f = 0; f < 5; ++f) { rs[f].x = 0.f; rs[f].y = 0.f; }

    // warm-up: ring slots 0..7 = products at rows h0-4 .. h0+3 (zero padded)
    #pragma unroll
    for (int k = 0; k < 8; ++k) {
        const int h = h0 - RAD + k;
        float2 iv = {0.f,0.f}, jv = {0.f,0.f};
        if (h >= 0 && h < HDIM) {
            iv = *(const float2*)(Ib + (size_t)h*WDIM);
            jv = *(const float2*)(Jb + (size_t)h*WDIM);
        }
        float2 pr[5];
        pr[0] = iv; pr[1] = jv;
        pr[2].x = iv.x*iv.x; pr[2].y = iv.y*iv.y;
        pr[3].x = jv.x*jv.x; pr[3].y = jv.y*jv.y;
        pr[4].x = iv.x*jv.x; pr[4].y = iv.y*jv.y;
        #pragma unroll
        for (int f = 0; f < 5; ++f) {
            ring[f][k] = pr[f];
            rs[f].x += pr[f].x; rs[f].y += pr[f].y;
        }
    }

    // one-step prefetch of row h0+4
    float2 niv = {0.f,0.f}, njv = {0.f,0.f};
    {
        const int hf = h0 + RAD;
        if (hf < HDIM) {
            niv = *(const float2*)(Ib + (size_t)hf*WDIM);
            njv = *(const float2*)(Jb + (size_t)hf*WDIM);
        }
    }

    // interleaved output: record of 5 halfs per voxel
    __half* ob = buf + ((size_t)(c*bufD + (d - d0 + RAD))*HWN + w0)*5;

    int i = 0;
    while (i < HT1) {
        #pragma unroll
        for (int p9 = 0; p9 < 9; ++p9) {   // i == p9 (mod 9) whenever body runs
            if (i < HT1) {
                const int h = h0 + i;
                const float2 iv = niv, jv = njv;
                // prefetch next row (hides HBM latency under LDS phase)
                niv.x = 0.f; niv.y = 0.f; njv.x = 0.f; njv.y = 0.f;
                const int hf2 = h + 1 + RAD;
                if (i + 1 < HT1 && hf2 < HDIM) {
                    niv = *(const float2*)(Ib + (size_t)hf2*WDIM);
                    njv = *(const float2*)(Jb + (size_t)hf2*WDIM);
                }
                float2 pr[5];
                pr[0] = iv; pr[1] = jv;
                pr[2].x = iv.x*iv.x; pr[2].y = iv.y*iv.y;
                pr[3].x = jv.x*jv.x; pr[3].y = jv.y*jv.y;
                pr[4].x = iv.x*jv.x; pr[4].y = iv.y*jv.y;
                float* rb = &row[s][h & 1][0][0];
                #pragma unroll
                for (int f = 0; f < 5; ++f) {
                    rs[f].x += pr[f].x; rs[f].y += pr[f].y;   // H-sum at h
                    *(float2*)(rb + f*NROW + 4 + w0) = rs[f];
                    rs[f].x -= ring[f][p9].x; rs[f].y -= ring[f][p9].y;  // drop h-4
                    ring[f][(p9+8)%9] = pr[f];                           // keep h+4
                }
                __syncthreads();               // single barrier: parity dbuf-safe
                float o0s[5], o1s[5];
                #pragma unroll
                for (int f = 0; f < 5; ++f) {
                    const float* q = rb + f*NROW + w0;   // window w0-4 .. w0+5
                    const float2 r0 = *(const float2*)(q + 0);
                    const float2 r1 = *(const float2*)(q + 2);
                    const float2 r2 = *(const float2*)(q + 4);
                    const float2 r3 = *(const float2*)(q + 6);
                    const float2 r4 = *(const float2*)(q + 8);
                    const float s9 = r0.x+r0.y+r1.x+r1.y+r2.x+r2.y+r3.x+r3.y+r4.x;
                    o0s[f] = s9;
                    o1s[f] = s9 - r0.x + r4.y;
                }
                // 20 B contiguous per lane -> 1280 B contiguous per wave
                __half2* pp = reinterpret_cast<__half2*>(ob + (size_t)h*WDIM*5);
                pp[0] = __floats2half2_rn(o0s[0], o0s[1]);
                pp[1] = __floats2half2_rn(o0s[2], o0s[3]);
                pp[2] = __floats2half2_rn(o0s[4], o1s[0]);
                pp[3] = __floats2half2_rn(o1s[1], o1s[2]);
                pp[4] = __floats2half2_rn(o1s[3], o1s[4]);
                ++i;
            }
        }
    }
}

// -------- K2: D-sum (register ring) + cc + block reduce — no LDS, no syncs --------
// grid: (HWN/256, nsub, C2); block: 256 threads
__global__ __launch_bounds__(256)
void k_dsum(const __half* __restrict__ buf, double* __restrict__ gacc,
            int d0, int bufD, int DS)
{
    const int tid = threadIdx.x;
    const int pix = blockIdx.x*256 + tid;     // (h,w) flat, HWN = 168*256 exact
    const int c   = blockIdx.z;
    const int ds0 = d0 + blockIdx.y*DS;

    // interleaved records: voxel (c, bd, pix) at ((c*bufD+bd)*HWN + pix)*5
    const __half* base = buf + ((size_t)c*bufD*HWN + (size_t)pix)*5;

    float ring[5][9];
    float rs[5] = {0.f,0.f,0.f,0.f,0.f};
    float acc = 0.f;

    // warm-up: slices ds0-4 .. ds0+3
    #pragma unroll
    for (int k = 0; k < 8; ++k) {
        const int dd = ds0 - RAD + k;
        float v[5] = {0.f,0.f,0.f,0.f,0.f};
        if ((unsigned)dd < (unsigned)DDIM) {
            const __half* pp = base + (size_t)(dd - d0 + RAD)*(size_t)HWN*5;
            #pragma unroll
            for (int f = 0; f < 5; ++f) v[f] = __half2float(pp[f]);
        }
        #pragma unroll
        for (int f = 0; f < 5; ++f) { ring[f][k] = v[f]; rs[f] += v[f]; }
    }

    int i = 0;
    while (i < DS) {
        #pragma unroll
        for (int p = 0; p < 9; ++p) {   // i == p (mod 9) whenever body runs
            if (i < DS) {
                const int dd = ds0 + i + RAD;
                float v[5] = {0.f,0.f,0.f,0.f,0.f};
                if (dd < DDIM) {
                    const __half* pp = base + (size_t)(dd - d0 + RAD)*(size_t)HWN*5;
                    #pragma unroll
                    for (int f = 0; f < 5; ++f) v[f] = __half2float(pp[f]);
                }
                float S[5];
                #pragma unroll
                for (int f = 0; f < 5; ++f) {
                    rs[f] += v[f];              // full 9x9x9 sum at dd-4
                    S[f] = rs[f];
                    rs[f] -= ring[f][p];        // drop slice dd-8
                    ring[f][(p+8)%9] = v[f];    // keep slice dd
                }
                const float uI    = S[0]*WINV;
                const float uJ    = S[1]*WINV;
                const float cross = S[4] - uJ*S[0];
                const float Iv    = S[2] - uI*S[0];
                const float Jv    = S[3] - uJ*S[1];
                acc += cross*cross / (Iv*Jv + 1e-5f);
                ++i;
            }
        }
    }

    // block reduction -> one double atomic per block
    __shared__ float wred[4];
    #pragma unroll
    for (int off = 32; off > 0; off >>= 1) acc += __shfl_down(acc, off);
    if ((tid & 63) == 0) wred[tid >> 6] = acc;
    __syncthreads();
    if (tid == 0) {
        const float sum = wred[0] + wred[1] + wred[2] + wred[3];
        atomicAdd(gacc, (double)sum);
    }
}

__global__ void k_fin(const double* __restrict__ gacc, float* __restrict__ out)
{
    out[0] = (float)(-gacc[0] / (double)((size_t)C2*DDIM*HDIM*WDIM));
}

extern "C" void kernel_launch(void* const* d_in, const int* in_sizes, int n_in,
                              void* d_out, int out_size, void* d_ws, size_t ws_size,
                              hipStream_t stream)
{
    if (n_in < 2) return;
    const float* I = (const float*)d_in[0];
    const float* J = (const float*)d_in[1];
    float* out = (float*)d_out;
    double* gacc = (double*)d_ws;
    __half* buf = (__half*)((char*)d_ws + 256);

    // choose D-chunk so the 5-half/voxel interleaved buffer fits ws
    static const int cands[] = {192, 96, 48, 24, 12, 6, 4, 2, 1};
    int Dc = 0;
    for (int c : cands) {
        const size_t need = 256 + (size_t)5*C2*(c+8)*HWN*sizeof(__half);
        if (need <= ws_size) { Dc = c; break; }
    }
    if (Dc == 0) return;  // ws too small — cannot run

    hipMemsetAsync(d_ws, 0, 256, stream);   // zero the double accumulator

    const int DS   = (Dc % 48 == 0) ? 48 : Dc;  // K2 sub-chunk along D
    const int nsub = Dc / DS;
    const int bufD = Dc + 8;

    for (int d0 = 0; d0 < DDIM; d0 += Dc) {
        const int dbeg = (d0 - RAD < 0) ? 0 : d0 - RAD;
        const int dend = (d0 + Dc + RAD > DDIM) ? DDIM : d0 + Dc + RAD;
        const int nd   = dend - dbeg;
        dim3 g1((nd + 1)/2, HDIM/HT1, C2);
        k_hwsum<<<g1, dim3(192,1,1), 0, stream>>>(I, J, buf, d0, dbeg, dend, bufD);
        dim3 g2(HWN/256, nsub, C2);
        k_dsum<<<g2, dim3(256,1,1), 0, stream>>>(buf, gacc, d0, bufD, DS);
    }
    k_fin<<<1,1,0,stream>>>(gacc, out);
}